// Round 25
// baseline (213.487 us; speedup 1.0000x reference)
//
#include <hip/hip_runtime.h>
#include <hip/hip_bf16.h>

// Grouped GEMM: out[n,g,k] = sum_d x[n*8+g, d] * W[g, k, d]
// FINAL (rounds 14/17/19/21-24: 213 us, 7x reproduced, clean counters:
// WRITE == ideal 264 MB, 0 bank conflicts, 0 spill, FETCH 165 MB).
// Wave specialization: 256x256 tile, BK=64, 12 waves (__launch_bounds__(768,3)).
//  - wid 0-7 consumers: pure MFMA (acc 8x4 in AGPRs) + ds_read + barrier,
//    setprio(1) around the MFMA cluster.
//  - wid 8-11 producers: A = 16 f32x4 loads + cvt_pk + 8 linear ds_write_b128,
//    2-DEEP pipeline (A(t+2) issued at t -> counted vmcnt, no latency
//    exposure); B = 8 glds16/thread from bf16 image (cvt_w pre-pass,
//    granule^(row&7) involution, L2-resident).
//  - ONE barrier per K-tile; vmcnt(16) keeps A(t+2) in flight across it.
//  - group-per-XCD bijective block swizzle; jt fastest for X L2 reuse.
// Trade-space fully mapped (R14-R20): 2-deep producer requires B-in-LDS
// (R15/R16 spill with B-in-reg); 1-deep producer is latency-bound (R18);
// half-tile 2-block loses co-residency + MFMA density (R20); longer barrier
// intervals need >160 KiB LDS. Family optimum.

namespace {

constexpr int NG   = 8;
constexpr int DIN  = 1024;
constexpr int DOUT = 1024;
constexpr int BM   = 256;
constexpr int BN   = 256;
constexpr int BK   = 64;
constexpr int NKT  = DIN / BK;            // 16
constexpr int ROWB = BK * 2;              // 128 B per LDS row
constexpr int TILE = BM * ROWB;           // 32 KiB per tile buffer
constexpr int LDS_BYTES = 4 * TILE;       // 128 KiB
constexpr int JTN  = DOUT / BN;           // 4
constexpr size_t WSB_BYTES = (size_t)NG * JTN * NKT * TILE;  // 16.78 MB

typedef __attribute__((ext_vector_type(8))) short bf16x8;
typedef __attribute__((ext_vector_type(4))) float f32x4;

__device__ __forceinline__ bf16x8 pack_bf16x8v(f32x4 lo, f32x4 hi) {
  union { __hip_bfloat162 h2[4]; bf16x8 v; } p;
  p.h2[0] = __float22bfloat162_rn(make_float2(lo.x, lo.y));
  p.h2[1] = __float22bfloat162_rn(make_float2(lo.z, lo.w));
  p.h2[2] = __float22bfloat162_rn(make_float2(hi.x, hi.y));
  p.h2[3] = __float22bfloat162_rn(make_float2(hi.z, hi.w));
  return p.v;
}

__device__ __forceinline__ void glds16(const void* g, void* l) {
  __builtin_amdgcn_global_load_lds(
      (const __attribute__((address_space(1))) unsigned int*)g,
      (__attribute__((address_space(3))) unsigned int*)l, 16, 0, 0);
}

#define FENCE() asm volatile("" ::: "memory")
#define BAR()   do { FENCE(); __builtin_amdgcn_s_barrier(); FENCE(); } while (0)
#define LGKM0() asm volatile("s_waitcnt lgkmcnt(0)" ::: "memory")
#define VM0()   asm volatile("s_waitcnt vmcnt(0)" ::: "memory")
#define VMC16() asm volatile("s_waitcnt vmcnt(16)" ::: "memory")
#define MFMA_(a, b, c) __builtin_amdgcn_mfma_f32_16x16x32_bf16((a), (b), (c), 0, 0, 0)

// ---------------- cvt_w: W f32 -> bf16 swizzled B-image (verified) ----------
__global__ __launch_bounds__(256)
void cvt_w_kernel(const float* __restrict__ W, char* __restrict__ wsB) {
  const int q    = (int)blockIdx.x * 256 + (int)threadIdx.x;  // u32 index
  const int tile = q >> 13;            // (g*4+jt)*16+kt; 8192 u32/tile
  const int q13  = q & 8191;
  const int r    = q13 >> 5;           // row 0..255
  const int cp   = q13 & 31;           // col-pair (bf16 cols 2cp,2cp+1)
  const int g    = tile >> 6;
  const int jt   = (tile >> 4) & 3;
  const int kt   = tile & 15;

  const float2 s = *(const float2*)(
      W + ((size_t)(g * DOUT + jt * BN + r)) * DIN + kt * 64 + 2 * cp);
  union { __hip_bfloat162 h; unsigned u; } pk;
  pk.h = __float22bfloat162_rn(make_float2(s.x, s.y));

  const int swzr = (r & 7) << 4;
  const int dstByte = r * ROWB + (((cp >> 2) * 16) ^ swzr) + (cp & 3) * 4;
  *(unsigned*)(wsB + (size_t)tile * TILE + dstByte) = pk.u;
}

// ---------------- producer helpers -----------------------------------------
#define ISSUE_A(TT, CUR)                                                       \
  { const float* Ai = aSrc + (size_t)(TT) * BK;                                \
    _Pragma("unroll")                                                          \
    for (int p = 0; p < 8; ++p) {                                              \
      aL[CUR][2 * p]     = *(const f32x4*)(Ai + p * ARSTR);                    \
      aL[CUR][2 * p + 1] = *(const f32x4*)(Ai + p * ARSTR + 4);                \
    } }

#define WRITE_A(CUR, DBUF)                                                     \
  { _Pragma("unroll")                                                          \
    for (int p = 0; p < 8; ++p)                                                \
      *(bf16x8*)((DBUF) + dst0 + p * 4096) =                                   \
          pack_bf16x8v(aL[CUR][2 * p], aL[CUR][2 * p + 1]); }

// WSB producer body for K-tile T: stage tile T+1 into buffer (T+1)&1.
// A(T+1) regs live in aL[CUR^1] (loaded at iter T-1); A(T+2) -> aL[CUR].
#define PBODY(T, CUR)                                                          \
  {                                                                            \
    char* const nA = smA + (((T) + 1) & 1) * TILE;                             \
    char* const nB = smB + (((T) + 1) & 1) * TILE;                             \
    const char* Bi = BgT + (size_t)((T) + 1) * TILE;                           \
    _Pragma("unroll")                                                          \
    for (int p = 0; p < 8; ++p)          /* B glds first (oldest) */           \
      glds16(Bi + dst0 + p * 4096, nB + dst0 + p * 4096);                      \
    FENCE();                                                                   \
    if ((T) + 2 < NKT) ISSUE_A((T) + 2, CUR);                                  \
    FENCE();                                                                   \
    WRITE_A((CUR) ^ 1, nA);              /* implicit counted vmcnt(24) */      \
    LGKM0();                                                                   \
    if ((T) + 2 < NKT) { VMC16(); } else { VM0(); }                            \
    BAR();                                                                     \
  }

// ---------------- gemm ------------------------------------------------------
template <bool WSB>
__global__ __launch_bounds__(768, 3)
void gemm_ws(const float* __restrict__ X, const float* __restrict__ W,
             const char* __restrict__ wsB, float* __restrict__ O) {
  extern __shared__ char smem[];
  char* const smA = smem;                  // [2][256][64] bf16, swizzled
  char* const smB = smem + 2 * TILE;

  // ---- block mapping: group == XCD (1024 blocks, 128/XCD), bijective
  const int bid = (int)blockIdx.x;
  const int swz = (bid & 7) * 128 + (bid >> 3);
  const int jt = swz & 3;                  // col panel [0,4) fastest (X reuse)
  const int it = (swz >> 2) & 31;          // row tile  [0,32)
  const int g  = swz >> 7;                 // group     [0,8)  == XCD

  const int n0 = it * BM;
  const int c0 = jt * BN;

  const int tid  = (int)threadIdx.x;
  const int lane = tid & 63;
  const int wid  = tid >> 6;               // 0-7 consumers, 8-11 producers

  if (wid < 8) {
    // ================= consumers: pure MFMA =================
    const int wr = (wid >> 2) & 1;
    const int wc = wid & 3;
    const int fr = lane & 15;
    const int fq = lane >> 4;
    const int colx0 = ((fq       ^ (fr & 7)) << 4);   // ks=0 granules 0-3
    const int colx1 = (((4 + fq) ^ (fr & 7)) << 4);   // ks=1 granules 4-7
    const int aRow0 = (wr * 128 + fr) * ROWB;
    const int bRow0 = (wc * 64  + fr) * ROWB;

    f32x4 acc[8][4];
#pragma unroll
    for (int m = 0; m < 8; ++m)
#pragma unroll
      for (int n = 0; n < 4; ++n) acc[m][n] = (f32x4){0.f, 0.f, 0.f, 0.f};

    BAR();   // matches producer prologue barrier

    for (int t = 0; t < NKT; ++t) {
      char* const cA = smA + (t & 1) * TILE;
      char* const cB = smB + (t & 1) * TILE;
#pragma unroll
      for (int ks = 0; ks < 2; ++ks) {
        const int cx = ks ? colx1 : colx0;
        bf16x8 bfr[4];
#pragma unroll
        for (int n = 0; n < 4; ++n)
          bfr[n] = *(const bf16x8*)(cB + bRow0 + n * 2048 + cx);
        __builtin_amdgcn_s_setprio(1);
#pragma unroll
        for (int m = 0; m < 8; ++m) {
          bf16x8 am = *(const bf16x8*)(cA + aRow0 + m * 2048 + cx);
#pragma unroll
          for (int n = 0; n < 4; ++n)
            acc[m][n] = MFMA_(am, bfr[n], acc[m][n]);
        }
        __builtin_amdgcn_s_setprio(0);
      }
      if (t + 1 < NKT) BAR();
    }

    // ---- epilogue: C/D layout col = lane&15, row = (lane>>4)*4 + reg (m89)
#pragma unroll
    for (int m = 0; m < 8; ++m) {
#pragma unroll
      for (int r = 0; r < 4; ++r) {
        const int row = wr * 128 + m * 16 + fq * 4 + r;
        float* orow = O + ((size_t)(n0 + row) * NG + g) * DOUT + c0 + wc * 64;
#pragma unroll
        for (int n = 0; n < 4; ++n) {
          orow[n * 16 + fr] = acc[m][n][r];
        }
      }
    }
  } else {
    // ================= producers (4 waves, 256 threads) =================
    const int ptid = tid - 512;            // 0..255
    const int r0   = ptid >> 3;            // base row 0..31 (+ p*32)
    const int sl   = ptid & 7;             // phys granule slot
    const int lg   = sl ^ (r0 & 7);        // logical k-granule (32%8==0)
    const int dst0 = ptid * 16;            // linear LDS dest

    const float* aSrc = X + ((size_t)(n0 + r0) * NG + g) * DIN + lg * 8;
    constexpr size_t ARSTR = (size_t)32 * NG * DIN;   // +32 tile rows
    const char* BgT = wsB + (size_t)((g * JTN + jt) * NKT) * TILE;
    const float* bSrc = W + ((size_t)(g * DOUT + c0 + r0)) * DIN + lg * 8;
    constexpr size_t BRSTR = (size_t)32 * DIN;

    f32x4 aL[2][16];

    if (WSB) {
      // ---- prologue: B(0) glds (oldest), A(0)->aL[0], A(1)->aL[1];
      //      write A(0) (implicit wait retires A(0) AND the older B(0)).
#pragma unroll
      for (int p = 0; p < 8; ++p)
        glds16(BgT + dst0 + p * 4096, smB + dst0 + p * 4096);
      FENCE();
      ISSUE_A(0, 0);
      ISSUE_A(1, 1);
      FENCE();
      WRITE_A(0, smA);                     // counted vmcnt(16): A(1) in flight
      LGKM0();
      BAR();

      for (int tt = 0; tt + 1 < NKT; tt += 2) {
        PBODY(tt, 0);                      // stages tile tt+1
        if (tt + 2 < NKT) PBODY(tt + 1, 1);
      }
      // 1 + 15 barriers == consumer's 16.
    } else {
      // ---- fallback (no ws): simple 1-deep reg-staged A and B
      f32x4 bL[16];
#pragma unroll
      for (int p = 0; p < 8; ++p) {
        aL[0][2 * p]     = *(const f32x4*)(aSrc + p * ARSTR);
        aL[0][2 * p + 1] = *(const f32x4*)(aSrc + p * ARSTR + 4);
        bL[2 * p]        = *(const f32x4*)(bSrc + p * BRSTR);
        bL[2 * p + 1]    = *(const f32x4*)(bSrc + p * BRSTR + 4);
      }
      WRITE_A(0, smA);
#pragma unroll
      for (int p = 0; p < 8; ++p)
        *(bf16x8*)(smB + dst0 + p * 4096) =
            pack_bf16x8v(bL[2 * p], bL[2 * p + 1]);
      LGKM0();
      BAR();
      for (int t = 0; t + 1 < NKT; ++t) {
        char* const nA = smA + ((t + 1) & 1) * TILE;
        char* const nB = smB + ((t + 1) & 1) * TILE;
        const float* Ai = aSrc + (size_t)(t + 1) * BK;
        const float* Bi = bSrc + (size_t)(t + 1) * BK;
#pragma unroll
        for (int p = 0; p < 8; ++p) {
          aL[0][2 * p]     = *(const f32x4*)(Ai + p * ARSTR);
          aL[0][2 * p + 1] = *(const f32x4*)(Ai + p * ARSTR + 4);
          bL[2 * p]        = *(const f32x4*)(Bi + p * BRSTR);
          bL[2 * p + 1]    = *(const f32x4*)(Bi + p * BRSTR + 4);
        }
        WRITE_A(0, nA);
#pragma unroll
        for (int p = 0; p < 8; ++p)
          *(bf16x8*)(nB + dst0 + p * 4096) =
              pack_bf16x8v(bL[2 * p], bL[2 * p + 1]);
        LGKM0();
        BAR();
      }
    }
  }
}

} // namespace

extern "C" void kernel_launch(void* const* d_in, const int* in_sizes, int n_in,
                              void* d_out, int out_size, void* d_ws, size_t ws_size,
                              hipStream_t stream) {
  (void)n_in; (void)out_size;
  const float* X = (const float*)d_in[0];
  const float* W = (const float*)d_in[1];
  float* O = (float*)d_out;

  const int tokens_total = in_sizes[0] / DIN;            // 65536
  const int ntok_per_g   = tokens_total / NG;            // 8192
  const int grid = NG * (ntok_per_g / BM) * (DOUT / BN); // 1024

  if (ws_size >= WSB_BYTES) {
    const int cvt_grid = (int)(WSB_BYTES / 4 / 256);     // 16384
    cvt_w_kernel<<<dim3(cvt_grid), dim3(256), 0, stream>>>(W, (char*)d_ws);
    (void)hipFuncSetAttribute((const void*)gemm_ws<true>,
                              hipFuncAttributeMaxDynamicSharedMemorySize,
                              LDS_BYTES);
    gemm_ws<true><<<dim3(grid), dim3(768), LDS_BYTES, stream>>>(
        X, W, (const char*)d_ws, O);
  } else {
    (void)hipFuncSetAttribute((const void*)gemm_ws<false>,
                              hipFuncAttributeMaxDynamicSharedMemorySize,
                              LDS_BYTES);
    gemm_ws<false><<<dim3(grid), dim3(768), LDS_BYTES, stream>>>(
        X, W, nullptr, O);
  }
}

// Round 26
// 213.064 us; speedup vs baseline: 1.0020x; 1.0020x over previous
//
#include <hip/hip_runtime.h>
#include <hip/hip_bf16.h>

// Grouped GEMM: out[n,g,k] = sum_d x[n*8+g, d] * W[g, k, d]
// FINAL (rounds 14/17/19/21-25: 213 us, 8x reproduced, clean counters:
// WRITE == ideal 264 MB, 0 bank conflicts, 0 spill, FETCH 165 MB).
// Wave specialization: 256x256 tile, BK=64, 12 waves (__launch_bounds__(768,3)).
//  - wid 0-7 consumers: pure MFMA (acc 8x4 in AGPRs) + ds_read + barrier,
//    setprio(1) around the MFMA cluster.
//  - wid 8-11 producers: A = 16 f32x4 loads + cvt_pk + 8 linear ds_write_b128,
//    2-DEEP pipeline (A(t+2) issued at t -> counted vmcnt, no latency
//    exposure); B = 8 glds16/thread from bf16 image (cvt_w pre-pass,
//    granule^(row&7) involution, L2-resident).
//  - ONE barrier per K-tile; vmcnt(16) keeps A(t+2) in flight across it.
//  - group-per-XCD bijective block swizzle; jt fastest for X L2 reuse.
// Trade-space fully mapped (R14-R20): 2-deep producer requires B-in-LDS
// (R15/R16 spill with B-in-reg); 1-deep producer is latency-bound (R18);
// half-tile 2-block loses co-residency + MFMA density (R20); longer barrier
// intervals need >160 KiB LDS. Family optimum.

namespace {

constexpr int NG   = 8;
constexpr int DIN  = 1024;
constexpr int DOUT = 1024;
constexpr int BM   = 256;
constexpr int BN   = 256;
constexpr int BK   = 64;
constexpr int NKT  = DIN / BK;            // 16
constexpr int ROWB = BK * 2;              // 128 B per LDS row
constexpr int TILE = BM * ROWB;           // 32 KiB per tile buffer
constexpr int LDS_BYTES = 4 * TILE;       // 128 KiB
constexpr int JTN  = DOUT / BN;           // 4
constexpr size_t WSB_BYTES = (size_t)NG * JTN * NKT * TILE;  // 16.78 MB

typedef __attribute__((ext_vector_type(8))) short bf16x8;
typedef __attribute__((ext_vector_type(4))) float f32x4;

__device__ __forceinline__ bf16x8 pack_bf16x8v(f32x4 lo, f32x4 hi) {
  union { __hip_bfloat162 h2[4]; bf16x8 v; } p;
  p.h2[0] = __float22bfloat162_rn(make_float2(lo.x, lo.y));
  p.h2[1] = __float22bfloat162_rn(make_float2(lo.z, lo.w));
  p.h2[2] = __float22bfloat162_rn(make_float2(hi.x, hi.y));
  p.h2[3] = __float22bfloat162_rn(make_float2(hi.z, hi.w));
  return p.v;
}

__device__ __forceinline__ void glds16(const void* g, void* l) {
  __builtin_amdgcn_global_load_lds(
      (const __attribute__((address_space(1))) unsigned int*)g,
      (__attribute__((address_space(3))) unsigned int*)l, 16, 0, 0);
}

#define FENCE() asm volatile("" ::: "memory")
#define BAR()   do { FENCE(); __builtin_amdgcn_s_barrier(); FENCE(); } while (0)
#define LGKM0() asm volatile("s_waitcnt lgkmcnt(0)" ::: "memory")
#define VM0()   asm volatile("s_waitcnt vmcnt(0)" ::: "memory")
#define VMC16() asm volatile("s_waitcnt vmcnt(16)" ::: "memory")
#define MFMA_(a, b, c) __builtin_amdgcn_mfma_f32_16x16x32_bf16((a), (b), (c), 0, 0, 0)

// ---------------- cvt_w: W f32 -> bf16 swizzled B-image (verified) ----------
__global__ __launch_bounds__(256)
void cvt_w_kernel(const float* __restrict__ W, char* __restrict__ wsB) {
  const int q    = (int)blockIdx.x * 256 + (int)threadIdx.x;  // u32 index
  const int tile = q >> 13;            // (g*4+jt)*16+kt; 8192 u32/tile
  const int q13  = q & 8191;
  const int r    = q13 >> 5;           // row 0..255
  const int cp   = q13 & 31;           // col-pair (bf16 cols 2cp,2cp+1)
  const int g    = tile >> 6;
  const int jt   = (tile >> 4) & 3;
  const int kt   = tile & 15;

  const float2 s = *(const float2*)(
      W + ((size_t)(g * DOUT + jt * BN + r)) * DIN + kt * 64 + 2 * cp);
  union { __hip_bfloat162 h; unsigned u; } pk;
  pk.h = __float22bfloat162_rn(make_float2(s.x, s.y));

  const int swzr = (r & 7) << 4;
  const int dstByte = r * ROWB + (((cp >> 2) * 16) ^ swzr) + (cp & 3) * 4;
  *(unsigned*)(wsB + (size_t)tile * TILE + dstByte) = pk.u;
}

// ---------------- producer helpers -----------------------------------------
#define ISSUE_A(TT, CUR)                                                       \
  { const float* Ai = aSrc + (size_t)(TT) * BK;                                \
    _Pragma("unroll")                                                          \
    for (int p = 0; p < 8; ++p) {                                              \
      aL[CUR][2 * p]     = *(const f32x4*)(Ai + p * ARSTR);                    \
      aL[CUR][2 * p + 1] = *(const f32x4*)(Ai + p * ARSTR + 4);                \
    } }

#define WRITE_A(CUR, DBUF)                                                     \
  { _Pragma("unroll")                                                          \
    for (int p = 0; p < 8; ++p)                                                \
      *(bf16x8*)((DBUF) + dst0 + p * 4096) =                                   \
          pack_bf16x8v(aL[CUR][2 * p], aL[CUR][2 * p + 1]); }

// WSB producer body for K-tile T: stage tile T+1 into buffer (T+1)&1.
// A(T+1) regs live in aL[CUR^1] (loaded at iter T-1); A(T+2) -> aL[CUR].
#define PBODY(T, CUR)                                                          \
  {                                                                            \
    char* const nA = smA + (((T) + 1) & 1) * TILE;                             \
    char* const nB = smB + (((T) + 1) & 1) * TILE;                             \
    const char* Bi = BgT + (size_t)((T) + 1) * TILE;                           \
    _Pragma("unroll")                                                          \
    for (int p = 0; p < 8; ++p)          /* B glds first (oldest) */           \
      glds16(Bi + dst0 + p * 4096, nB + dst0 + p * 4096);                      \
    FENCE();                                                                   \
    if ((T) + 2 < NKT) ISSUE_A((T) + 2, CUR);                                  \
    FENCE();                                                                   \
    WRITE_A((CUR) ^ 1, nA);              /* implicit counted vmcnt(24) */      \
    LGKM0();                                                                   \
    if ((T) + 2 < NKT) { VMC16(); } else { VM0(); }                            \
    BAR();                                                                     \
  }

// ---------------- gemm ------------------------------------------------------
template <bool WSB>
__global__ __launch_bounds__(768, 3)
void gemm_ws(const float* __restrict__ X, const float* __restrict__ W,
             const char* __restrict__ wsB, float* __restrict__ O) {
  extern __shared__ char smem[];
  char* const smA = smem;                  // [2][256][64] bf16, swizzled
  char* const smB = smem + 2 * TILE;

  // ---- block mapping: group == XCD (1024 blocks, 128/XCD), bijective
  const int bid = (int)blockIdx.x;
  const int swz = (bid & 7) * 128 + (bid >> 3);
  const int jt = swz & 3;                  // col panel [0,4) fastest (X reuse)
  const int it = (swz >> 2) & 31;          // row tile  [0,32)
  const int g  = swz >> 7;                 // group     [0,8)  == XCD

  const int n0 = it * BM;
  const int c0 = jt * BN;

  const int tid  = (int)threadIdx.x;
  const int lane = tid & 63;
  const int wid  = tid >> 6;               // 0-7 consumers, 8-11 producers

  if (wid < 8) {
    // ================= consumers: pure MFMA =================
    const int wr = (wid >> 2) & 1;
    const int wc = wid & 3;
    const int fr = lane & 15;
    const int fq = lane >> 4;
    const int colx0 = ((fq       ^ (fr & 7)) << 4);   // ks=0 granules 0-3
    const int colx1 = (((4 + fq) ^ (fr & 7)) << 4);   // ks=1 granules 4-7
    const int aRow0 = (wr * 128 + fr) * ROWB;
    const int bRow0 = (wc * 64  + fr) * ROWB;

    f32x4 acc[8][4];
#pragma unroll
    for (int m = 0; m < 8; ++m)
#pragma unroll
      for (int n = 0; n < 4; ++n) acc[m][n] = (f32x4){0.f, 0.f, 0.f, 0.f};

    BAR();   // matches producer prologue barrier

    for (int t = 0; t < NKT; ++t) {
      char* const cA = smA + (t & 1) * TILE;
      char* const cB = smB + (t & 1) * TILE;
#pragma unroll
      for (int ks = 0; ks < 2; ++ks) {
        const int cx = ks ? colx1 : colx0;
        bf16x8 bfr[4];
#pragma unroll
        for (int n = 0; n < 4; ++n)
          bfr[n] = *(const bf16x8*)(cB + bRow0 + n * 2048 + cx);
        __builtin_amdgcn_s_setprio(1);
#pragma unroll
        for (int m = 0; m < 8; ++m) {
          bf16x8 am = *(const bf16x8*)(cA + aRow0 + m * 2048 + cx);
#pragma unroll
          for (int n = 0; n < 4; ++n)
            acc[m][n] = MFMA_(am, bfr[n], acc[m][n]);
        }
        __builtin_amdgcn_s_setprio(0);
      }
      if (t + 1 < NKT) BAR();
    }

    // ---- epilogue: C/D layout col = lane&15, row = (lane>>4)*4 + reg (m89)
#pragma unroll
    for (int m = 0; m < 8; ++m) {
#pragma unroll
      for (int r = 0; r < 4; ++r) {
        const int row = wr * 128 + m * 16 + fq * 4 + r;
        float* orow = O + ((size_t)(n0 + row) * NG + g) * DOUT + c0 + wc * 64;
#pragma unroll
        for (int n = 0; n < 4; ++n) {
          orow[n * 16 + fr] = acc[m][n][r];
        }
      }
    }
  } else {
    // ================= producers (4 waves, 256 threads) =================
    const int ptid = tid - 512;            // 0..255
    const int r0   = ptid >> 3;            // base row 0..31 (+ p*32)
    const int sl   = ptid & 7;             // phys granule slot
    const int lg   = sl ^ (r0 & 7);        // logical k-granule (32%8==0)
    const int dst0 = ptid * 16;            // linear LDS dest

    const float* aSrc = X + ((size_t)(n0 + r0) * NG + g) * DIN + lg * 8;
    constexpr size_t ARSTR = (size_t)32 * NG * DIN;   // +32 tile rows
    const char* BgT = wsB + (size_t)((g * JTN + jt) * NKT) * TILE;
    const float* bSrc = W + ((size_t)(g * DOUT + c0 + r0)) * DIN + lg * 8;
    constexpr size_t BRSTR = (size_t)32 * DIN;

    f32x4 aL[2][16];

    if (WSB) {
      // ---- prologue: B(0) glds (oldest), A(0)->aL[0], A(1)->aL[1];
      //      write A(0) (implicit wait retires A(0) AND the older B(0)).
#pragma unroll
      for (int p = 0; p < 8; ++p)
        glds16(BgT + dst0 + p * 4096, smB + dst0 + p * 4096);
      FENCE();
      ISSUE_A(0, 0);
      ISSUE_A(1, 1);
      FENCE();
      WRITE_A(0, smA);                     // counted vmcnt(16): A(1) in flight
      LGKM0();
      BAR();

      for (int tt = 0; tt + 1 < NKT; tt += 2) {
        PBODY(tt, 0);                      // stages tile tt+1
        if (tt + 2 < NKT) PBODY(tt + 1, 1);
      }
      // 1 + 15 barriers == consumer's 16.
    } else {
      // ---- fallback (no ws): simple 1-deep reg-staged A and B
      f32x4 bL[16];
#pragma unroll
      for (int p = 0; p < 8; ++p) {
        aL[0][2 * p]     = *(const f32x4*)(aSrc + p * ARSTR);
        aL[0][2 * p + 1] = *(const f32x4*)(aSrc + p * ARSTR + 4);
        bL[2 * p]        = *(const f32x4*)(bSrc + p * BRSTR);
        bL[2 * p + 1]    = *(const f32x4*)(bSrc + p * BRSTR + 4);
      }
      WRITE_A(0, smA);
#pragma unroll
      for (int p = 0; p < 8; ++p)
        *(bf16x8*)(smB + dst0 + p * 4096) =
            pack_bf16x8v(bL[2 * p], bL[2 * p + 1]);
      LGKM0();
      BAR();
      for (int t = 0; t + 1 < NKT; ++t) {
        char* const nA = smA + ((t + 1) & 1) * TILE;
        char* const nB = smB + ((t + 1) & 1) * TILE;
        const float* Ai = aSrc + (size_t)(t + 1) * BK;
        const float* Bi = bSrc + (size_t)(t + 1) * BK;
#pragma unroll
        for (int p = 0; p < 8; ++p) {
          aL[0][2 * p]     = *(const f32x4*)(Ai + p * ARSTR);
          aL[0][2 * p + 1] = *(const f32x4*)(Ai + p * ARSTR + 4);
          bL[2 * p]        = *(const f32x4*)(Bi + p * BRSTR);
          bL[2 * p + 1]    = *(const f32x4*)(Bi + p * BRSTR + 4);
        }
        WRITE_A(0, nA);
#pragma unroll
        for (int p = 0; p < 8; ++p)
          *(bf16x8*)(nB + dst0 + p * 4096) =
              pack_bf16x8v(bL[2 * p], bL[2 * p + 1]);
        LGKM0();
        BAR();
      }
    }
  }
}

} // namespace

extern "C" void kernel_launch(void* const* d_in, const int* in_sizes, int n_in,
                              void* d_out, int out_size, void* d_ws, size_t ws_size,
                              hipStream_t stream) {
  (void)n_in; (void)out_size;
  const float* X = (const float*)d_in[0];
  const float* W = (const float*)d_in[1];
  float* O = (float*)d_out;

  const int tokens_total = in_sizes[0] / DIN;            // 65536
  const int ntok_per_g   = tokens_total / NG;            // 8192
  const int grid = NG * (ntok_per_g / BM) * (DOUT / BN); // 1024

  if (ws_size >= WSB_BYTES) {
    const int cvt_grid = (int)(WSB_BYTES / 4 / 256);     // 16384
    cvt_w_kernel<<<dim3(cvt_grid), dim3(256), 0, stream>>>(W, (char*)d_ws);
    (void)hipFuncSetAttribute((const void*)gemm_ws<true>,
                              hipFuncAttributeMaxDynamicSharedMemorySize,
                              LDS_BYTES);
    gemm_ws<true><<<dim3(grid), dim3(768), LDS_BYTES, stream>>>(
        X, W, (const char*)d_ws, O);
  } else {
    (void)hipFuncSetAttribute((const void*)gemm_ws<false>,
                              hipFuncAttributeMaxDynamicSharedMemorySize,
                              LDS_BYTES);
    gemm_ws<false><<<dim3(grid), dim3(768), LDS_BYTES, stream>>>(
        X, W, nullptr, O);
  }
}

// Round 27
// 212.328 us; speedup vs baseline: 1.0055x; 1.0035x over previous
//
#include <hip/hip_runtime.h>
#include <hip/hip_bf16.h>

// Grouped GEMM: out[n,g,k] = sum_d x[n*8+g, d] * W[g, k, d]
// FINAL (rounds 14/17/19/21-26: 213 us, 9x reproduced, clean counters:
// WRITE == ideal 264 MB, 0 bank conflicts, 0 spill, FETCH 165 MB).
// Wave specialization: 256x256 tile, BK=64, 12 waves (__launch_bounds__(768,3)).
//  - wid 0-7 consumers: pure MFMA (acc 8x4 in AGPRs) + ds_read + barrier,
//    setprio(1) around the MFMA cluster.
//  - wid 8-11 producers: A = 16 f32x4 loads + cvt_pk + 8 linear ds_write_b128,
//    2-DEEP pipeline (A(t+2) issued at t -> counted vmcnt, no latency
//    exposure); B = 8 glds16/thread from bf16 image (cvt_w pre-pass,
//    granule^(row&7) involution, L2-resident).
//  - ONE barrier per K-tile; vmcnt(16) keeps A(t+2) in flight across it.
//  - group-per-XCD bijective block swizzle; jt fastest for X L2 reuse.
// Trade-space fully mapped (R14-R20): 2-deep producer requires B-in-LDS
// (R15/R16 spill with B-in-reg); 1-deep producer is latency-bound (R18);
// half-tile 2-block loses co-residency + MFMA density (R20); longer barrier
// intervals need >160 KiB LDS. Family optimum.

namespace {

constexpr int NG   = 8;
constexpr int DIN  = 1024;
constexpr int DOUT = 1024;
constexpr int BM   = 256;
constexpr int BN   = 256;
constexpr int BK   = 64;
constexpr int NKT  = DIN / BK;            // 16
constexpr int ROWB = BK * 2;              // 128 B per LDS row
constexpr int TILE = BM * ROWB;           // 32 KiB per tile buffer
constexpr int LDS_BYTES = 4 * TILE;       // 128 KiB
constexpr int JTN  = DOUT / BN;           // 4
constexpr size_t WSB_BYTES = (size_t)NG * JTN * NKT * TILE;  // 16.78 MB

typedef __attribute__((ext_vector_type(8))) short bf16x8;
typedef __attribute__((ext_vector_type(4))) float f32x4;

__device__ __forceinline__ bf16x8 pack_bf16x8v(f32x4 lo, f32x4 hi) {
  union { __hip_bfloat162 h2[4]; bf16x8 v; } p;
  p.h2[0] = __float22bfloat162_rn(make_float2(lo.x, lo.y));
  p.h2[1] = __float22bfloat162_rn(make_float2(lo.z, lo.w));
  p.h2[2] = __float22bfloat162_rn(make_float2(hi.x, hi.y));
  p.h2[3] = __float22bfloat162_rn(make_float2(hi.z, hi.w));
  return p.v;
}

__device__ __forceinline__ void glds16(const void* g, void* l) {
  __builtin_amdgcn_global_load_lds(
      (const __attribute__((address_space(1))) unsigned int*)g,
      (__attribute__((address_space(3))) unsigned int*)l, 16, 0, 0);
}

#define FENCE() asm volatile("" ::: "memory")
#define BAR()   do { FENCE(); __builtin_amdgcn_s_barrier(); FENCE(); } while (0)
#define LGKM0() asm volatile("s_waitcnt lgkmcnt(0)" ::: "memory")
#define VM0()   asm volatile("s_waitcnt vmcnt(0)" ::: "memory")
#define VMC16() asm volatile("s_waitcnt vmcnt(16)" ::: "memory")
#define MFMA_(a, b, c) __builtin_amdgcn_mfma_f32_16x16x32_bf16((a), (b), (c), 0, 0, 0)

// ---------------- cvt_w: W f32 -> bf16 swizzled B-image (verified) ----------
__global__ __launch_bounds__(256)
void cvt_w_kernel(const float* __restrict__ W, char* __restrict__ wsB) {
  const int q    = (int)blockIdx.x * 256 + (int)threadIdx.x;  // u32 index
  const int tile = q >> 13;            // (g*4+jt)*16+kt; 8192 u32/tile
  const int q13  = q & 8191;
  const int r    = q13 >> 5;           // row 0..255
  const int cp   = q13 & 31;           // col-pair (bf16 cols 2cp,2cp+1)
  const int g    = tile >> 6;
  const int jt   = (tile >> 4) & 3;
  const int kt   = tile & 15;

  const float2 s = *(const float2*)(
      W + ((size_t)(g * DOUT + jt * BN + r)) * DIN + kt * 64 + 2 * cp);
  union { __hip_bfloat162 h; unsigned u; } pk;
  pk.h = __float22bfloat162_rn(make_float2(s.x, s.y));

  const int swzr = (r & 7) << 4;
  const int dstByte = r * ROWB + (((cp >> 2) * 16) ^ swzr) + (cp & 3) * 4;
  *(unsigned*)(wsB + (size_t)tile * TILE + dstByte) = pk.u;
}

// ---------------- producer helpers -----------------------------------------
#define ISSUE_A(TT, CUR)                                                       \
  { const float* Ai = aSrc + (size_t)(TT) * BK;                                \
    _Pragma("unroll")                                                          \
    for (int p = 0; p < 8; ++p) {                                              \
      aL[CUR][2 * p]     = *(const f32x4*)(Ai + p * ARSTR);                    \
      aL[CUR][2 * p + 1] = *(const f32x4*)(Ai + p * ARSTR + 4);                \
    } }

#define WRITE_A(CUR, DBUF)                                                     \
  { _Pragma("unroll")                                                          \
    for (int p = 0; p < 8; ++p)                                                \
      *(bf16x8*)((DBUF) + dst0 + p * 4096) =                                   \
          pack_bf16x8v(aL[CUR][2 * p], aL[CUR][2 * p + 1]); }

// WSB producer body for K-tile T: stage tile T+1 into buffer (T+1)&1.
// A(T+1) regs live in aL[CUR^1] (loaded at iter T-1); A(T+2) -> aL[CUR].
#define PBODY(T, CUR)                                                          \
  {                                                                            \
    char* const nA = smA + (((T) + 1) & 1) * TILE;                             \
    char* const nB = smB + (((T) + 1) & 1) * TILE;                             \
    const char* Bi = BgT + (size_t)((T) + 1) * TILE;                           \
    _Pragma("unroll")                                                          \
    for (int p = 0; p < 8; ++p)          /* B glds first (oldest) */           \
      glds16(Bi + dst0 + p * 4096, nB + dst0 + p * 4096);                      \
    FENCE();                                                                   \
    if ((T) + 2 < NKT) ISSUE_A((T) + 2, CUR);                                  \
    FENCE();                                                                   \
    WRITE_A((CUR) ^ 1, nA);              /* implicit counted vmcnt(24) */      \
    LGKM0();                                                                   \
    if ((T) + 2 < NKT) { VMC16(); } else { VM0(); }                            \
    BAR();                                                                     \
  }

// ---------------- gemm ------------------------------------------------------
template <bool WSB>
__global__ __launch_bounds__(768, 3)
void gemm_ws(const float* __restrict__ X, const float* __restrict__ W,
             const char* __restrict__ wsB, float* __restrict__ O) {
  extern __shared__ char smem[];
  char* const smA = smem;                  // [2][256][64] bf16, swizzled
  char* const smB = smem + 2 * TILE;

  // ---- block mapping: group == XCD (1024 blocks, 128/XCD), bijective
  const int bid = (int)blockIdx.x;
  const int swz = (bid & 7) * 128 + (bid >> 3);
  const int jt = swz & 3;                  // col panel [0,4) fastest (X reuse)
  const int it = (swz >> 2) & 31;          // row tile  [0,32)
  const int g  = swz >> 7;                 // group     [0,8)  == XCD

  const int n0 = it * BM;
  const int c0 = jt * BN;

  const int tid  = (int)threadIdx.x;
  const int lane = tid & 63;
  const int wid  = tid >> 6;               // 0-7 consumers, 8-11 producers

  if (wid < 8) {
    // ================= consumers: pure MFMA =================
    const int wr = (wid >> 2) & 1;
    const int wc = wid & 3;
    const int fr = lane & 15;
    const int fq = lane >> 4;
    const int colx0 = ((fq       ^ (fr & 7)) << 4);   // ks=0 granules 0-3
    const int colx1 = (((4 + fq) ^ (fr & 7)) << 4);   // ks=1 granules 4-7
    const int aRow0 = (wr * 128 + fr) * ROWB;
    const int bRow0 = (wc * 64  + fr) * ROWB;

    f32x4 acc[8][4];
#pragma unroll
    for (int m = 0; m < 8; ++m)
#pragma unroll
      for (int n = 0; n < 4; ++n) acc[m][n] = (f32x4){0.f, 0.f, 0.f, 0.f};

    BAR();   // matches producer prologue barrier

    for (int t = 0; t < NKT; ++t) {
      char* const cA = smA + (t & 1) * TILE;
      char* const cB = smB + (t & 1) * TILE;
#pragma unroll
      for (int ks = 0; ks < 2; ++ks) {
        const int cx = ks ? colx1 : colx0;
        bf16x8 bfr[4];
#pragma unroll
        for (int n = 0; n < 4; ++n)
          bfr[n] = *(const bf16x8*)(cB + bRow0 + n * 2048 + cx);
        __builtin_amdgcn_s_setprio(1);
#pragma unroll
        for (int m = 0; m < 8; ++m) {
          bf16x8 am = *(const bf16x8*)(cA + aRow0 + m * 2048 + cx);
#pragma unroll
          for (int n = 0; n < 4; ++n)
            acc[m][n] = MFMA_(am, bfr[n], acc[m][n]);
        }
        __builtin_amdgcn_s_setprio(0);
      }
      if (t + 1 < NKT) BAR();
    }

    // ---- epilogue: C/D layout col = lane&15, row = (lane>>4)*4 + reg (m89)
#pragma unroll
    for (int m = 0; m < 8; ++m) {
#pragma unroll
      for (int r = 0; r < 4; ++r) {
        const int row = wr * 128 + m * 16 + fq * 4 + r;
        float* orow = O + ((size_t)(n0 + row) * NG + g) * DOUT + c0 + wc * 64;
#pragma unroll
        for (int n = 0; n < 4; ++n) {
          orow[n * 16 + fr] = acc[m][n][r];
        }
      }
    }
  } else {
    // ================= producers (4 waves, 256 threads) =================
    const int ptid = tid - 512;            // 0..255
    const int r0   = ptid >> 3;            // base row 0..31 (+ p*32)
    const int sl   = ptid & 7;             // phys granule slot
    const int lg   = sl ^ (r0 & 7);        // logical k-granule (32%8==0)
    const int dst0 = ptid * 16;            // linear LDS dest

    const float* aSrc = X + ((size_t)(n0 + r0) * NG + g) * DIN + lg * 8;
    constexpr size_t ARSTR = (size_t)32 * NG * DIN;   // +32 tile rows
    const char* BgT = wsB + (size_t)((g * JTN + jt) * NKT) * TILE;
    const float* bSrc = W + ((size_t)(g * DOUT + c0 + r0)) * DIN + lg * 8;
    constexpr size_t BRSTR = (size_t)32 * DIN;

    f32x4 aL[2][16];

    if (WSB) {
      // ---- prologue: B(0) glds (oldest), A(0)->aL[0], A(1)->aL[1];
      //      write A(0) (implicit wait retires A(0) AND the older B(0)).
#pragma unroll
      for (int p = 0; p < 8; ++p)
        glds16(BgT + dst0 + p * 4096, smB + dst0 + p * 4096);
      FENCE();
      ISSUE_A(0, 0);
      ISSUE_A(1, 1);
      FENCE();
      WRITE_A(0, smA);                     // counted vmcnt(16): A(1) in flight
      LGKM0();
      BAR();

      for (int tt = 0; tt + 1 < NKT; tt += 2) {
        PBODY(tt, 0);                      // stages tile tt+1
        if (tt + 2 < NKT) PBODY(tt + 1, 1);
      }
      // 1 + 15 barriers == consumer's 16.
    } else {
      // ---- fallback (no ws): simple 1-deep reg-staged A and B
      f32x4 bL[16];
#pragma unroll
      for (int p = 0; p < 8; ++p) {
        aL[0][2 * p]     = *(const f32x4*)(aSrc + p * ARSTR);
        aL[0][2 * p + 1] = *(const f32x4*)(aSrc + p * ARSTR + 4);
        bL[2 * p]        = *(const f32x4*)(bSrc + p * BRSTR);
        bL[2 * p + 1]    = *(const f32x4*)(bSrc + p * BRSTR + 4);
      }
      WRITE_A(0, smA);
#pragma unroll
      for (int p = 0; p < 8; ++p)
        *(bf16x8*)(smB + dst0 + p * 4096) =
            pack_bf16x8v(bL[2 * p], bL[2 * p + 1]);
      LGKM0();
      BAR();
      for (int t = 0; t + 1 < NKT; ++t) {
        char* const nA = smA + ((t + 1) & 1) * TILE;
        char* const nB = smB + ((t + 1) & 1) * TILE;
        const float* Ai = aSrc + (size_t)(t + 1) * BK;
        const float* Bi = bSrc + (size_t)(t + 1) * BK;
#pragma unroll
        for (int p = 0; p < 8; ++p) {
          aL[0][2 * p]     = *(const f32x4*)(Ai + p * ARSTR);
          aL[0][2 * p + 1] = *(const f32x4*)(Ai + p * ARSTR + 4);
          bL[2 * p]        = *(const f32x4*)(Bi + p * BRSTR);
          bL[2 * p + 1]    = *(const f32x4*)(Bi + p * BRSTR + 4);
        }
        WRITE_A(0, nA);
#pragma unroll
        for (int p = 0; p < 8; ++p)
          *(bf16x8*)(nB + dst0 + p * 4096) =
              pack_bf16x8v(bL[2 * p], bL[2 * p + 1]);
        LGKM0();
        BAR();
      }
    }
  }
}

} // namespace

extern "C" void kernel_launch(void* const* d_in, const int* in_sizes, int n_in,
                              void* d_out, int out_size, void* d_ws, size_t ws_size,
                              hipStream_t stream) {
  (void)n_in; (void)out_size;
  const float* X = (const float*)d_in[0];
  const float* W = (const float*)d_in[1];
  float* O = (float*)d_out;

  const int tokens_total = in_sizes[0] / DIN;            // 65536
  const int ntok_per_g   = tokens_total / NG;            // 8192
  const int grid = NG * (ntok_per_g / BM) * (DOUT / BN); // 1024

  if (ws_size >= WSB_BYTES) {
    const int cvt_grid = (int)(WSB_BYTES / 4 / 256);     // 16384
    cvt_w_kernel<<<dim3(cvt_grid), dim3(256), 0, stream>>>(W, (char*)d_ws);
    (void)hipFuncSetAttribute((const void*)gemm_ws<true>,
                              hipFuncAttributeMaxDynamicSharedMemorySize,
                              LDS_BYTES);
    gemm_ws<true><<<dim3(grid), dim3(768), LDS_BYTES, stream>>>(
        X, W, (const char*)d_ws, O);
  } else {
    (void)hipFuncSetAttribute((const void*)gemm_ws<false>,
                              hipFuncAttributeMaxDynamicSharedMemorySize,
                              LDS_BYTES);
    gemm_ws<false><<<dim3(grid), dim3(768), LDS_BYTES, stream>>>(
        X, W, nullptr, O);
  }
}